// Round 1
// baseline (76.789 us; speedup 1.0000x reference)
//
#include <hip/hip_runtime.h>
#include <hip/hip_bf16.h>

// GAT layer, B=4, N=256, IN=128, H=4, D=64.
// Index algebra of the reference's tile/view construction:
//   e[b,hp,i,j] = lrelu_0.2( f1[b*1024 + hp*256 + i] + f2[b*1024 + (i&3)*256 + j] )
//   f1[b,n,h] = sum_d a[d]    * Wh[b,n,h,d]
//   f2[b,n,h] = sum_d a[64+d] * Wh[b,n,h,d]     (flat layout [B, N*H] = b*1024+n*4+h)
//   att = softmax_j(mask(adj[b,i,j]==0 -> -inf, e))
//   out[b,i,hp*64+d] = sum_j att[j] * Wh[b,j,hp*64+d]

// ---------------- Kernel A: Wh = h @ W, plus f1/f2 via wave reduction ----------
// grid: 128 blocks (8 rows each of the 1024 (b,n) rows), block: 256 threads.
__global__ __launch_bounds__(256) void gat_wh_kernel(
    const float* __restrict__ h, const float* __restrict__ W,
    const float* __restrict__ a,
    float* __restrict__ Wh, float* __restrict__ f1, float* __restrict__ f2) {
  const int row0 = blockIdx.x * 8;   // global row = b*256+n
  const int c = threadIdx.x;         // output column 0..255  (head = c>>6, d = c&63)

  __shared__ float sh[8][128];
  for (int t = threadIdx.x; t < 8 * 128; t += 256)
    sh[t >> 7][t & 127] = h[row0 * 128 + t];
  __syncthreads();

  float acc[8];
#pragma unroll
  for (int r = 0; r < 8; r++) acc[r] = 0.f;

  for (int k = 0; k < 128; k++) {
    float w = W[k * 256 + c];
#pragma unroll
    for (int r = 0; r < 8; r++) acc[r] += sh[r][k] * w;
  }

  const int d = c & 63;
  const int wv = c >> 6;             // wave index == head index
  const float a1v = a[d];
  const float a2v = a[64 + d];

#pragma unroll
  for (int r = 0; r < 8; r++) {
    Wh[(row0 + r) * 256 + c] = acc[r];
    float p1 = a1v * acc[r];
    float p2 = a2v * acc[r];
#pragma unroll
    for (int off = 32; off > 0; off >>= 1) {
      p1 += __shfl_xor(p1, off, 64);
      p2 += __shfl_xor(p2, off, 64);
    }
    if (d == 0) {
      f1[(row0 + r) * 4 + wv] = p1;   // = f1flat[b*1024 + n*4 + h]
      f2[(row0 + r) * 4 + wv] = p2;
    }
  }
}

// ---------------- Kernel B: logits + masked softmax + att @ Wh -----------------
// grid: B*H*(N/4) = 1024 blocks; block handles (b, hp, rows i0..i0+3), 256 thr.
__global__ __launch_bounds__(256) void gat_attn_kernel(
    const float* __restrict__ Wh, const float* __restrict__ f1,
    const float* __restrict__ f2, const int* __restrict__ adj,
    float* __restrict__ out) {
  const int blk = blockIdx.x;
  const int it = blk & 63;          // i-tile
  const int hp = (blk >> 6) & 3;    // head
  const int b  = blk >> 8;
  const int i0 = it * 4;

  const int tid = threadIdx.x;
  const int lane = tid & 63;
  const int wv = tid >> 6;          // row-within-tile for phase 1; seg for phase 2
  const int i = i0 + wv;

  __shared__ float att[4][256];
  __shared__ float red[4][4][64];
  __shared__ float sinv[4];

  // ---- Phase 1: wave wv builds softmax row i ----
  const float s1 = f1[b * 1024 + hp * 256 + i];
  const float* f2row = f2 + b * 1024 + (i & 3) * 256;
  const int* adjrow = adj + (b * 256 + i) * 256;

  float e[4];
  float m = -1e30f;
#pragma unroll
  for (int q = 0; q < 4; q++) {
    int j = lane + q * 64;
    float ev = s1 + f2row[j];
    ev = ev > 0.f ? ev : 0.2f * ev;            // leaky relu 0.2
    ev = (adjrow[j] == 0) ? -1e30f : ev;       // mask
    e[q] = ev;
    m = fmaxf(m, ev);
  }
#pragma unroll
  for (int off = 32; off > 0; off >>= 1) m = fmaxf(m, __shfl_xor(m, off, 64));

  float s = 0.f;
#pragma unroll
  for (int q = 0; q < 4; q++) {
    float ex = __expf(e[q] - m);
    s += ex;
    att[wv][lane + q * 64] = ex;
  }
#pragma unroll
  for (int off = 32; off > 0; off >>= 1) s += __shfl_xor(s, off, 64);
  if (lane == 0) sinv[wv] = 1.f / s;
  __syncthreads();

  // ---- Phase 2: att @ Wh ----
  // thread: d = tid&63, seg = tid>>6 (j-range seg*64..seg*64+63)
  const int d = lane;
  const int seg = wv;
  const float* whp = Wh + b * 65536 + hp * 64 + d;   // Wh[b, j, hp*64+d], j-stride 256
  float acc[4] = {0.f, 0.f, 0.f, 0.f};
  for (int jj = 0; jj < 64; jj++) {
    int j = seg * 64 + jj;
    float whv = whp[j * 256];
#pragma unroll
    for (int r = 0; r < 4; r++) acc[r] += att[r][j] * whv;
  }
#pragma unroll
  for (int r = 0; r < 4; r++) red[r][seg][d] = acc[r];
  __syncthreads();

  // reduce over segs; thread -> (r = tid>>6, d = tid&63)
  const int r = wv;
  float o = (red[r][0][d] + red[r][1][d]) + (red[r][2][d] + red[r][3][d]);
  o *= sinv[r];
  out[(b * 256 + i0 + r) * 256 + hp * 64 + d] = o;
}

extern "C" void kernel_launch(void* const* d_in, const int* in_sizes, int n_in,
                              void* d_out, int out_size, void* d_ws, size_t ws_size,
                              hipStream_t stream) {
  const float* h   = (const float*)d_in[0];   // [4,256,128]
  const int*   adj = (const int*)d_in[1];     // [4,256,256]
  const float* W   = (const float*)d_in[2];   // [128,256]
  const float* a   = (const float*)d_in[3];   // [128,1]
  float* out = (float*)d_out;                 // [4,256,256]

  float* Wh = (float*)d_ws;                   // 262144 floats
  float* f1 = Wh + 262144;                    // 4096 floats
  float* f2 = f1 + 4096;                      // 4096 floats

  gat_wh_kernel<<<128, 256, 0, stream>>>(h, W, a, Wh, f1, f2);
  gat_attn_kernel<<<1024, 256, 0, stream>>>(Wh, f1, f2, adj, out);
}